// Round 1
// baseline (4285.151 us; speedup 1.0000x reference)
//
#include <hip/hip_runtime.h>
#include <math.h>

#define Bn 4096
#define Tn 40
#define Hn 128
#define ROWS 16
#define NGRID 100
#define PI_F 3.14159265358979f
#define SQRT_2PI_F 2.50662827f

struct NetW {
  const float *Wih0,*Whh0,*bih0,*bhh0,*Wih1,*Whh1,*bih1,*bhh1,*Wh,*bh;
};

__device__ __forceinline__ float sigm(float x){ return 1.0f/(1.0f+__expf(-x)); }
__device__ __forceinline__ float dot4(float4 a, float4 b){
  return a.x*b.x + a.y*b.y + a.z*b.z + a.w*b.w;
}

// ---------------- fused 2-layer GRU encoder + head, one net per blockIdx.y ----
__global__ __launch_bounds__(256)
void gru_fused(const float* __restrict__ x, NetW Wd, NetW Wsd,
               float* __restrict__ mu_out, float* __restrict__ sig_out)
{
  const NetW W = (blockIdx.y == 0) ? Wd : Wsd;
  const int r0   = blockIdx.x * ROWS;
  const int tid  = threadIdx.x;
  const int jj   = tid & 127;     // hidden column this thread owns
  const int half = tid >> 7;      // which 8-row group
  const int rbase = half * 8;

  __shared__ float h0[ROWS][Hn];
  __shared__ float h1[ROWS][Hn];
  __shared__ float s1s[ROWS][Hn];
  __shared__ float s0t[ROWS][Hn];
  __shared__ float xs[ROWS];

  #pragma unroll
  for (int i = 0; i < 8; ++i) {
    h0[rbase+i][jj] = 0.f; h1[rbase+i][jj] = 0.f; s1s[rbase+i][jj] = 0.f;
  }

  // hoisted per-column scalars
  const float wi0_r = W.Wih0[jj], wi0_z = W.Wih0[128+jj], wi0_n = W.Wih0[256+jj];
  const float bi0_r = W.bih0[jj], bi0_z = W.bih0[128+jj], bi0_n = W.bih0[256+jj];
  const float bh0_r = W.bhh0[jj], bh0_z = W.bhh0[128+jj], bh0_n = W.bhh0[256+jj];
  const float c1_r  = W.bih1[jj]     + W.bhh1[jj];
  const float c1_z  = W.bih1[128+jj] + W.bhh1[128+jj];
  const float bi1_n = W.bih1[256+jj];
  const float bh1_n = W.bhh1[256+jj];

  const float4* Wh0r = (const float4*)(W.Whh0 + (jj      )*Hn);
  const float4* Wh0z = (const float4*)(W.Whh0 + (128+jj  )*Hn);
  const float4* Wh0n = (const float4*)(W.Whh0 + (256+jj  )*Hn);
  const float4* Wi1r = (const float4*)(W.Wih1 + (jj      )*Hn);
  const float4* Wi1z = (const float4*)(W.Wih1 + (128+jj  )*Hn);
  const float4* Wi1n = (const float4*)(W.Wih1 + (256+jj  )*Hn);
  const float4* Wh1r = (const float4*)(W.Whh1 + (jj      )*Hn);
  const float4* Wh1z = (const float4*)(W.Whh1 + (128+jj  )*Hn);
  const float4* Wh1n = (const float4*)(W.Whh1 + (256+jj  )*Hn);

  for (int t = 0; t < Tn; ++t) {
    if (tid < ROWS) xs[tid] = x[(size_t)(r0 + tid) * Tn + t];
    __syncthreads();

    // -------- layer 0: gh = h0 @ Whh0^T (this thread: rows rbase..rbase+7, cols jj,128+jj,256+jj)
    float ar[8] = {0,0,0,0,0,0,0,0}, az[8] = {0,0,0,0,0,0,0,0}, an[8] = {0,0,0,0,0,0,0,0};
    #pragma unroll 4
    for (int k4 = 0; k4 < Hn/4; ++k4) {
      const float4 wr = Wh0r[k4], wz = Wh0z[k4], wn = Wh0n[k4];
      #pragma unroll
      for (int i = 0; i < 8; ++i) {
        const float4 hv = *reinterpret_cast<const float4*>(&h0[rbase+i][k4<<2]);
        ar[i] += dot4(hv, wr);
        az[i] += dot4(hv, wz);
        an[i] += dot4(hv, wn);
      }
    }
    float hnew[8];
    #pragma unroll
    for (int i = 0; i < 8; ++i) {
      const int r = rbase + i;
      const float xv = xs[r];
      const float gr = sigm(xv*wi0_r + bi0_r + ar[i] + bh0_r);
      const float gz = sigm(xv*wi0_z + bi0_z + az[i] + bh0_z);
      const float gn = tanhf(xv*wi0_n + bi0_n + gr*(an[i] + bh0_n));
      hnew[i] = (1.0f - gz)*gn + gz*h0[r][jj];
    }
    __syncthreads();
    #pragma unroll
    for (int i = 0; i < 8; ++i) { const int r = rbase+i; h0[r][jj] = hnew[i]; s0t[r][jj] = hnew[i]; }
    __syncthreads();

    // -------- layer 1: xg = s0t @ Wih1^T ; gh = h1 @ Whh1^T
    float br[8] = {0,0,0,0,0,0,0,0}, bz[8] = {0,0,0,0,0,0,0,0};
    float bxn[8] = {0,0,0,0,0,0,0,0}, bhn[8] = {0,0,0,0,0,0,0,0};
    #pragma unroll 4
    for (int k4 = 0; k4 < Hn/4; ++k4) {
      const float4 xr = Wi1r[k4], xz = Wi1z[k4], xn = Wi1n[k4];
      const float4 hr = Wh1r[k4], hz = Wh1z[k4], hn = Wh1n[k4];
      #pragma unroll
      for (int i = 0; i < 8; ++i) {
        const float4 sv = *reinterpret_cast<const float4*>(&s0t[rbase+i][k4<<2]);
        const float4 hv = *reinterpret_cast<const float4*>(&h1[rbase+i][k4<<2]);
        br[i]  += dot4(sv, xr) + dot4(hv, hr);
        bz[i]  += dot4(sv, xz) + dot4(hv, hz);
        bxn[i] += dot4(sv, xn);
        bhn[i] += dot4(hv, hn);
      }
    }
    #pragma unroll
    for (int i = 0; i < 8; ++i) {
      const int r = rbase + i;
      const float gr = sigm(br[i] + c1_r);
      const float gz = sigm(bz[i] + c1_z);
      const float gn = tanhf(bxn[i] + bi1_n + gr*(bhn[i] + bh1_n));
      hnew[i] = (1.0f - gz)*gn + gz*h1[r][jj];
    }
    __syncthreads();
    #pragma unroll
    for (int i = 0; i < 8; ++i) { const int r = rbase+i; h1[r][jj] = hnew[i]; s1s[r][jj] += hnew[i]; }
    __syncthreads();
  }

  // -------- head: enc = [h0, h1, mean_t(s1)]  ->  v = enc . Wh + bh
  const int row = tid >> 4;   // 0..15
  const int l   = tid & 15;
  float p = 0.f;
  for (int j = l; j < Hn; j += 16) {
    p += h0[row][j]*W.Wh[j] + h1[row][j]*W.Wh[128+j] + s1s[row][j]*(1.0f/Tn)*W.Wh[256+j];
  }
  #pragma unroll
  for (int o = 8; o > 0; o >>= 1) p += __shfl_xor(p, o);
  if (l == 0) {
    float v = p + W.bh[0];
    v = fminf(fmaxf(v, -20.f), 20.f);
    const int b = r0 + row;
    if (blockIdx.y == 0) mu_out[b] = v;
    else                 sig_out[b] = log1pf(__expf(v)) + 1e-4f;
  }
}

// ---------------- regularized incomplete beta (NR continued fraction) --------
__device__ float betacf_(float a, float b, float x)
{
  const float FPMIN = 1e-30f, EPS = 3e-7f;
  const float qab = a + b, qap = a + 1.f, qam = a - 1.f;
  float c = 1.f;
  float d = 1.f - qab * x / qap;
  if (fabsf(d) < FPMIN) d = FPMIN;
  d = 1.f / d;
  float h = d;
  for (int m = 1; m <= 100; ++m) {
    const float m2 = 2.f * m;
    float aa = m * (b - m) * x / ((qam + m2) * (a + m2));
    d = 1.f + aa * d; if (fabsf(d) < FPMIN) d = FPMIN;
    c = 1.f + aa / c; if (fabsf(c) < FPMIN) c = FPMIN;
    d = 1.f / d; h *= d * c;
    aa = -(a + m) * (qab + m) * x / ((a + m2) * (qap + m2));
    d = 1.f + aa * d; if (fabsf(d) < FPMIN) d = FPMIN;
    c = 1.f + aa / c; if (fabsf(c) < FPMIN) c = FPMIN;
    d = 1.f / d;
    const float del = d * c; h *= del;
    if (fabsf(del - 1.f) < EPS) break;
  }
  return h;
}

__device__ float betainc_(float a, float b, float x, float cx)
{
  if (x  <= 0.f) return 0.f;
  if (cx <= 0.f) return 1.f;
  const float lx  = (x  > 0.5f) ? log1pf(-cx) : logf(x);
  const float lcx = (cx > 0.5f) ? log1pf(-x)  : logf(cx);
  const float bt = expf(lgammaf(a+b) - lgammaf(a) - lgammaf(b) + a*lx + b*lcx);
  if (x < (a + 1.f) / (a + b + 2.f)) return bt * betacf_(a, b, x) / a;
  else                               return 1.f - bt * betacf_(b, a, cx) / b;
}

// ---------------- per-sample NLL + Student-t CDF + partial reductions --------
__global__ __launch_bounds__(256)
void stats_k(const float* __restrict__ mu, const float* __restrict__ sig,
             const float* __restrict__ dX, const float* __restrict__ dTp,
             const float* __restrict__ log_nu,
             float* __restrict__ cdf_out, float* __restrict__ parts)
{
  const int tid = threadIdx.x;
  const int b = blockIdx.x * 256 + tid;
  const float dT = dTp[0];
  const float df = fminf(fmaxf(expf(log_nu[0]), 2.1f), 30.0f);

  const float m = mu[b], s = sig[b];
  const float scale = s * sqrtf(dT);
  const float y  = (dX[b] - m * dT) / scale;
  const float y2 = y * y;
  const float lp = lgammaf((df + 1.f) * 0.5f) - lgammaf(df * 0.5f)
                 - 0.5f * logf(df * PI_F) - logf(scale)
                 - (df + 1.f) * 0.5f * log1pf(y2 / df);
  const float den = df + y2;
  const float xb = df / den, cxb = y2 / den;
  const float ib = betainc_(0.5f * df, 0.5f, xb, cxb);
  float cdf = (y <= 0.f) ? 0.5f * ib : 1.f - 0.5f * ib;
  cdf = fminf(fmaxf(cdf, 1e-6f), 1.f - 1e-6f);
  cdf_out[b] = cdf;

  __shared__ float red[256];
  red[tid] = lp; __syncthreads();
  for (int o = 128; o > 0; o >>= 1) { if (tid < o) red[tid] += red[tid + o]; __syncthreads(); }
  if (tid == 0) parts[blockIdx.x] = red[0];
  __syncthreads();
  red[tid] = cdf; __syncthreads();
  for (int o = 128; o > 0; o >>= 1) { if (tid < o) red[tid] += red[tid + o]; __syncthreads(); }
  if (tid == 0) parts[16 + blockIdx.x] = red[0];
  __syncthreads();
  red[tid] = cdf * cdf; __syncthreads();
  for (int o = 128; o > 0; o >>= 1) { if (tid < o) red[tid] += red[tid + o]; __syncthreads(); }
  if (tid == 0) parts[32 + blockIdx.x] = red[0];
}

// ---------------- KDE penalty + final scalar ---------------------------------
__global__ __launch_bounds__(256)
void final_k(const float* __restrict__ cdf, const float* __restrict__ parts,
             float* __restrict__ out)
{
  __shared__ float cd[Bn];
  __shared__ float sh[256];
  __shared__ float s_nll, s_hbw;
  const int tid = threadIdx.x;
  for (int i = tid; i < Bn; i += 256) cd[i] = cdf[i];
  if (tid == 0) {
    float slp = 0.f, sc = 0.f, sc2 = 0.f;
    for (int i = 0; i < 16; ++i) { slp += parts[i]; sc += parts[16+i]; sc2 += parts[32+i]; }
    const float nll  = -slp / (float)Bn;
    const float mean = sc / (float)Bn;
    const float var  = (sc2 - (float)Bn * mean * mean) / (float)(Bn - 1);
    const float sd   = sqrtf(fmaxf(var, 0.f));
    s_hbw = 1.06f * sd * powf((float)Bn, -0.2f) + 1e-5f;
    s_nll = nll;
  }
  __syncthreads();
  const float hbw = s_hbw, inv = 1.0f / hbw;

  const int g = tid & 127, part = tid >> 7;
  float acc = 0.f;
  if (g < NGRID) {
    const float u = (float)g / (float)(NGRID - 1);
    const int b0 = part * (Bn/2);
    for (int b = b0; b < b0 + Bn/2; ++b) {
      const float d = (u - cd[b]) * inv;
      acc += __expf(-0.5f * d * d);
    }
  }
  sh[tid] = acc; __syncthreads();
  float pen_part = 0.f;
  if (tid < 128) {
    const float tot = sh[tid] + sh[tid + 128];
    if (g < NGRID) {
      const float f = tot / (SQRT_2PI_F * (float)Bn * hbw);
      const float dd = f - 1.0f;
      pen_part = dd * dd * (1.0f / (float)NGRID);
    }
  }
  __syncthreads();
  sh[tid] = pen_part; __syncthreads();
  for (int o = 128; o > 0; o >>= 1) { if (tid < o) sh[tid] += sh[tid + o]; __syncthreads(); }
  if (tid == 0) out[0] = s_nll + 100.0f * sh[0];
}

// ---------------- launcher ---------------------------------------------------
extern "C" void kernel_launch(void* const* d_in, const int* in_sizes, int n_in,
                              void* d_out, int out_size, void* d_ws, size_t ws_size,
                              hipStream_t stream)
{
  const float* x      = (const float*)d_in[0];
  const float* dX     = (const float*)d_in[1];
  const float* dT     = (const float*)d_in[2];
  NetW Wd { (const float*)d_in[3],  (const float*)d_in[4],  (const float*)d_in[5],
            (const float*)d_in[6],  (const float*)d_in[7],  (const float*)d_in[8],
            (const float*)d_in[9],  (const float*)d_in[10], (const float*)d_in[11],
            (const float*)d_in[12] };
  NetW Ws { (const float*)d_in[13], (const float*)d_in[14], (const float*)d_in[15],
            (const float*)d_in[16], (const float*)d_in[17], (const float*)d_in[18],
            (const float*)d_in[19], (const float*)d_in[20], (const float*)d_in[21],
            (const float*)d_in[22] };
  const float* log_nu = (const float*)d_in[23];

  float* w    = (float*)d_ws;
  float* mu   = w;
  float* sig  = w + Bn;
  float* cdf  = w + 2 * Bn;
  float* parts= w + 3 * Bn;   // 48 floats

  gru_fused<<<dim3(Bn/ROWS, 2), 256, 0, stream>>>(x, Wd, Ws, mu, sig);
  stats_k  <<<dim3(Bn/256), 256, 0, stream>>>(mu, sig, dX, dT, log_nu, cdf, parts);
  final_k  <<<dim3(1), 256, 0, stream>>>(cdf, parts, (float*)d_out);
}

// Round 2
// 320.165 us; speedup vs baseline: 13.3842x; 13.3842x over previous
//
#include <hip/hip_runtime.h>
#include <math.h>

#define Bn 4096
#define Tn 40
#define Hn 128
#define RB 32
#define NGRID 100
#define PI_F 3.14159265358979f
#define SQRT_2PI_F 2.50662827f

typedef _Float16 f16;
typedef __attribute__((ext_vector_type(8))) _Float16 f16x8;
typedef __attribute__((ext_vector_type(4))) float f32x4;

struct GruW {
  const f16 *fWhh0, *fWih1, *fWhh1;     // fragment-layout fp16 weight buffers
  const float *Wih0, *bih0, *bhh0, *bih1, *bhh1, *Wh, *bh;
};
struct WSrc { const float* m[6]; };

__device__ __forceinline__ float sigm_f(float x){ return 1.0f/(1.0f+__expf(-x)); }
__device__ __forceinline__ float tanh_f(float x){ return 1.0f - 2.0f/(__expf(2.0f*x)+1.0f); }

// ---- fp32 [384][128] -> fp16 MFMA-B fragment layout: frag[(nt*4+ks)*64+lane][8]
//      lane l holds B[k=ks*32+(l>>4)*8+j][n=nt*16+(l&15)] = W[n][k]
__global__ __launch_bounds__(256)
void wconv_k(WSrc S, f16* __restrict__ dst)
{
  const int m  = blockIdx.x / 24;
  const int nt = blockIdx.x % 24;
  const int ks = threadIdx.x >> 6;
  const int l  = threadIdx.x & 63;
  const float* src = S.m[m] + (size_t)(nt*16 + (l&15))*Hn + ks*32 + (l>>4)*8;
  f16x8 o;
  #pragma unroll
  for (int jj = 0; jj < 8; ++jj) o[jj] = (f16)src[jj];
  *((f16x8*)(dst + (size_t)m*49152) + ((nt*4 + ks)*64 + l)) = o;
}

// ---- fused 2-layer GRU recurrence via MFMA; 1 block = 32 batch rows of one net
__global__ __launch_bounds__(512, 2)
void gru_mfma(const float* __restrict__ x, GruW Wd, GruW Ws,
              float* __restrict__ mu_out, float* __restrict__ sig_out)
{
  const int net = blockIdx.x >> 7;
  const int r0  = (blockIdx.x & 127) * RB;
  const GruW W  = net ? Ws : Wd;
  const int tid = threadIdx.x;
  const int w   = tid >> 6;        // wave 0..7, owns gate-col block w*16..w*16+15
  const int l   = tid & 63;

  __shared__ __align__(16) char smem[49152];
  char*  h0b  = smem;                         // [32][128] f16, XOR-swizzled
  char*  h1b  = smem + 8192;
  float* xall = (float*)(smem + 16384);       // [32][40]
  float* enc  = (float*)smem;                 // [32][384] fp32 (after loop)

  for (int o = tid*16; o < 16384; o += 512*16) *(int4*)(smem + o) = make_int4(0,0,0,0);
  for (int i = tid; i < RB*Tn; i += 512) {
    int r = i / Tn, c = i - r*Tn;
    xall[i] = x[(size_t)(r0 + r)*Tn + c];
  }

  const int j = w*16 + (l & 15);   // hidden column 0..127
  const float wi0_r = W.Wih0[j], wi0_z = W.Wih0[Hn+j], wi0_n = W.Wih0[2*Hn+j];
  const float b0_r  = W.bih0[j]      + W.bhh0[j];
  const float b0_z  = W.bih0[Hn+j]   + W.bhh0[Hn+j];
  const float b0_ni = W.bih0[2*Hn+j], b0_nh = W.bhh0[2*Hn+j];
  const float b1_r  = W.bih1[j]      + W.bhh1[j];
  const float b1_z  = W.bih1[Hn+j]   + W.bhh1[Hn+j];
  const float b1_ni = W.bih1[2*Hn+j], b1_nh = W.bhh1[2*Hn+j];

  const f16x8* F0  = (const f16x8*)W.fWhh0;
  const f16x8* F1h = (const f16x8*)W.fWhh1;
  const f16x8* F1i = (const f16x8*)W.fWih1;
  f16x8 w0[3][4], w1h[3][4];
  #pragma unroll
  for (int g = 0; g < 3; ++g)
    #pragma unroll
    for (int ks = 0; ks < 4; ++ks) {
      const int idx = ((w + 8*g)*4 + ks)*64 + l;
      w0[g][ks]  = F0[idx];
      w1h[g][ks] = F1h[idx];
    }

  float h0r[8] = {0,0,0,0,0,0,0,0}, h1r[8] = {0,0,0,0,0,0,0,0}, s1r[8] = {0,0,0,0,0,0,0,0};

  const int xorm  = (l & 7) << 4;
  const int abase = (l & 15)*256 + (l >> 4)*16;

  __syncthreads();

  for (int t = 0; t < Tn; ++t) {
    // stream Wih1 fragments (L2-resident; consumed in L1 phase)
    f16x8 w1i[3][4];
    #pragma unroll
    for (int g = 0; g < 3; ++g)
      #pragma unroll
      for (int ks = 0; ks < 4; ++ks)
        w1i[g][ks] = F1i[((w + 8*g)*4 + ks)*64 + l];

    // ---- layer0: gh0 = h0 @ Whh0^T
    f32x4 acc0[3][2];
    #pragma unroll
    for (int g = 0; g < 3; ++g) { acc0[g][0] = (f32x4){0,0,0,0}; acc0[g][1] = (f32x4){0,0,0,0}; }
    #pragma unroll
    for (int mt = 0; mt < 2; ++mt)
      #pragma unroll
      for (int ks = 0; ks < 4; ++ks) {
        const f16x8 a = *(const f16x8*)(h0b + ((abase + mt*4096 + ks*64) ^ xorm));
        #pragma unroll
        for (int g = 0; g < 3; ++g)
          acc0[g][mt] = __builtin_amdgcn_mfma_f32_16x16x32_f16(a, w0[g][ks], acc0[g][mt], 0, 0, 0);
      }
    __syncthreads();                       // all waves done reading old h0

    #pragma unroll
    for (int mt = 0; mt < 2; ++mt)
      #pragma unroll
      for (int q = 0; q < 4; ++q) {
        const int row = mt*16 + (l >> 4)*4 + q;
        const float xv = xall[row*Tn + t];
        const float rg = sigm_f(fmaf(xv, wi0_r, b0_r) + acc0[0][mt][q]);
        const float zg = sigm_f(fmaf(xv, wi0_z, b0_z) + acc0[1][mt][q]);
        const float ng = tanh_f(fmaf(xv, wi0_n, b0_ni) + rg*(acc0[2][mt][q] + b0_nh));
        const float hv = (1.0f - zg)*ng + zg*h0r[mt*4+q];
        h0r[mt*4+q] = hv;
        *(f16*)(h0b + ((row*256 + j*2) ^ ((row & 7) << 4))) = (f16)hv;
      }
    __syncthreads();                       // new h0 visible

    // ---- layer1: xg1 = h0new @ Wih1^T ; gh1 = h1 @ Whh1^T
    f32x4 aRZ[2][2], aXN[2], aHN[2];
    aRZ[0][0]=(f32x4){0,0,0,0}; aRZ[0][1]=(f32x4){0,0,0,0};
    aRZ[1][0]=(f32x4){0,0,0,0}; aRZ[1][1]=(f32x4){0,0,0,0};
    aXN[0]=(f32x4){0,0,0,0}; aXN[1]=(f32x4){0,0,0,0};
    aHN[0]=(f32x4){0,0,0,0}; aHN[1]=(f32x4){0,0,0,0};
    #pragma unroll
    for (int mt = 0; mt < 2; ++mt)
      #pragma unroll
      for (int ks = 0; ks < 4; ++ks) {
        const int ad = (abase + mt*4096 + ks*64) ^ xorm;
        const f16x8 a0 = *(const f16x8*)(h0b + ad);
        const f16x8 a1 = *(const f16x8*)(h1b + ad);
        aRZ[0][mt] = __builtin_amdgcn_mfma_f32_16x16x32_f16(a0, w1i[0][ks], aRZ[0][mt], 0,0,0);
        aRZ[0][mt] = __builtin_amdgcn_mfma_f32_16x16x32_f16(a1, w1h[0][ks], aRZ[0][mt], 0,0,0);
        aRZ[1][mt] = __builtin_amdgcn_mfma_f32_16x16x32_f16(a0, w1i[1][ks], aRZ[1][mt], 0,0,0);
        aRZ[1][mt] = __builtin_amdgcn_mfma_f32_16x16x32_f16(a1, w1h[1][ks], aRZ[1][mt], 0,0,0);
        aXN[mt]    = __builtin_amdgcn_mfma_f32_16x16x32_f16(a0, w1i[2][ks], aXN[mt], 0,0,0);
        aHN[mt]    = __builtin_amdgcn_mfma_f32_16x16x32_f16(a1, w1h[2][ks], aHN[mt], 0,0,0);
      }
    __syncthreads();                       // all waves done reading old h1

    #pragma unroll
    for (int mt = 0; mt < 2; ++mt)
      #pragma unroll
      for (int q = 0; q < 4; ++q) {
        const float rg = sigm_f(aRZ[0][mt][q] + b1_r);
        const float zg = sigm_f(aRZ[1][mt][q] + b1_z);
        const float ng = tanh_f(aXN[mt][q] + b1_ni + rg*(aHN[mt][q] + b1_nh));
        const float hv = (1.0f - zg)*ng + zg*h1r[mt*4+q];
        h1r[mt*4+q] = hv;
        s1r[mt*4+q] += hv;
        const int row = mt*16 + (l >> 4)*4 + q;
        *(f16*)(h1b + ((row*256 + j*2) ^ ((row & 7) << 4))) = (f16)hv;
      }
    // no barrier needed: next L0 touches only h0; h1 readers are 2 barriers away
  }

  __syncthreads();
  #pragma unroll
  for (int mt = 0; mt < 2; ++mt)
    #pragma unroll
    for (int q = 0; q < 4; ++q) {
      const int row = mt*16 + (l >> 4)*4 + q;
      enc[row*384 + j]        = h0r[mt*4+q];
      enc[row*384 + Hn + j]   = h1r[mt*4+q];
      enc[row*384 + 2*Hn + j] = s1r[mt*4+q] * (1.0f/Tn);
    }
  __syncthreads();

  const int row16 = tid >> 4, l16 = tid & 15;
  float p = 0.f;
  for (int c = l16; c < 384; c += 16) p += enc[row16*384 + c] * W.Wh[c];
  p += __shfl_xor(p, 8); p += __shfl_xor(p, 4); p += __shfl_xor(p, 2); p += __shfl_xor(p, 1);
  if (l16 == 0) {
    const float v = fminf(fmaxf(p + W.bh[0], -20.f), 20.f);
    const int b = r0 + row16;
    if (net == 0) mu_out[b] = v;
    else          sig_out[b] = log1pf(__expf(v)) + 1e-4f;
  }
}

// ---------------- regularized incomplete beta (NR continued fraction) --------
__device__ float betacf_(float a, float b, float x)
{
  const float FPMIN = 1e-30f, EPS = 3e-7f;
  const float qab = a + b, qap = a + 1.f, qam = a - 1.f;
  float c = 1.f;
  float d = 1.f - qab * x / qap;
  if (fabsf(d) < FPMIN) d = FPMIN;
  d = 1.f / d;
  float h = d;
  for (int m = 1; m <= 100; ++m) {
    const float m2 = 2.f * m;
    float aa = m * (b - m) * x / ((qam + m2) * (a + m2));
    d = 1.f + aa * d; if (fabsf(d) < FPMIN) d = FPMIN;
    c = 1.f + aa / c; if (fabsf(c) < FPMIN) c = FPMIN;
    d = 1.f / d; h *= d * c;
    aa = -(a + m) * (qab + m) * x / ((a + m2) * (qap + m2));
    d = 1.f + aa * d; if (fabsf(d) < FPMIN) d = FPMIN;
    c = 1.f + aa / c; if (fabsf(c) < FPMIN) c = FPMIN;
    d = 1.f / d;
    const float del = d * c; h *= del;
    if (fabsf(del - 1.f) < EPS) break;
  }
  return h;
}

__device__ float betainc_(float a, float b, float x, float cx)
{
  if (x  <= 0.f) return 0.f;
  if (cx <= 0.f) return 1.f;
  const float lx  = (x  > 0.5f) ? log1pf(-cx) : logf(x);
  const float lcx = (cx > 0.5f) ? log1pf(-x)  : logf(cx);
  const float bt = expf(lgammaf(a+b) - lgammaf(a) - lgammaf(b) + a*lx + b*lcx);
  if (x < (a + 1.f) / (a + b + 2.f)) return bt * betacf_(a, b, x) / a;
  else                               return 1.f - bt * betacf_(b, a, cx) / b;
}

__global__ __launch_bounds__(256)
void stats_k(const float* __restrict__ mu, const float* __restrict__ sig,
             const float* __restrict__ dX, const float* __restrict__ dTp,
             const float* __restrict__ log_nu,
             float* __restrict__ cdf_out, float* __restrict__ parts)
{
  const int tid = threadIdx.x;
  const int b = blockIdx.x * 256 + tid;
  const float dT = dTp[0];
  const float df = fminf(fmaxf(expf(log_nu[0]), 2.1f), 30.0f);

  const float m = mu[b], s = sig[b];
  const float scale = s * sqrtf(dT);
  const float y  = (dX[b] - m * dT) / scale;
  const float y2 = y * y;
  const float lp = lgammaf((df + 1.f) * 0.5f) - lgammaf(df * 0.5f)
                 - 0.5f * logf(df * PI_F) - logf(scale)
                 - (df + 1.f) * 0.5f * log1pf(y2 / df);
  const float den = df + y2;
  const float xb = df / den, cxb = y2 / den;
  const float ib = betainc_(0.5f * df, 0.5f, xb, cxb);
  float cdf = (y <= 0.f) ? 0.5f * ib : 1.f - 0.5f * ib;
  cdf = fminf(fmaxf(cdf, 1e-6f), 1.f - 1e-6f);
  cdf_out[b] = cdf;

  __shared__ float red[256];
  red[tid] = lp; __syncthreads();
  for (int o = 128; o > 0; o >>= 1) { if (tid < o) red[tid] += red[tid + o]; __syncthreads(); }
  if (tid == 0) parts[blockIdx.x] = red[0];
  __syncthreads();
  red[tid] = cdf; __syncthreads();
  for (int o = 128; o > 0; o >>= 1) { if (tid < o) red[tid] += red[tid + o]; __syncthreads(); }
  if (tid == 0) parts[16 + blockIdx.x] = red[0];
  __syncthreads();
  red[tid] = cdf * cdf; __syncthreads();
  for (int o = 128; o > 0; o >>= 1) { if (tid < o) red[tid] += red[tid + o]; __syncthreads(); }
  if (tid == 0) parts[32 + blockIdx.x] = red[0];
}

__global__ __launch_bounds__(256)
void final_k(const float* __restrict__ cdf, const float* __restrict__ parts,
             float* __restrict__ out)
{
  __shared__ float cd[Bn];
  __shared__ float sh[256];
  __shared__ float s_nll, s_hbw;
  const int tid = threadIdx.x;
  for (int i = tid; i < Bn; i += 256) cd[i] = cdf[i];
  if (tid == 0) {
    float slp = 0.f, sc = 0.f, sc2 = 0.f;
    for (int i = 0; i < 16; ++i) { slp += parts[i]; sc += parts[16+i]; sc2 += parts[32+i]; }
    const float nll  = -slp / (float)Bn;
    const float mean = sc / (float)Bn;
    const float var  = (sc2 - (float)Bn * mean * mean) / (float)(Bn - 1);
    const float sd   = sqrtf(fmaxf(var, 0.f));
    s_hbw = 1.06f * sd * powf((float)Bn, -0.2f) + 1e-5f;
    s_nll = nll;
  }
  __syncthreads();
  const float hbw = s_hbw, inv = 1.0f / hbw;

  const int g = tid & 127, part = tid >> 7;
  float acc = 0.f;
  if (g < NGRID) {
    const float u = (float)g / (float)(NGRID - 1);
    const int b0 = part * (Bn/2);
    for (int b = b0; b < b0 + Bn/2; ++b) {
      const float d = (u - cd[b]) * inv;
      acc += __expf(-0.5f * d * d);
    }
  }
  sh[tid] = acc; __syncthreads();
  float pen_part = 0.f;
  if (tid < 128) {
    const float tot = sh[tid] + sh[tid + 128];
    if (g < NGRID) {
      const float f = tot / (SQRT_2PI_F * (float)Bn * hbw);
      const float dd = f - 1.0f;
      pen_part = dd * dd * (1.0f / (float)NGRID);
    }
  }
  __syncthreads();
  sh[tid] = pen_part; __syncthreads();
  for (int o = 128; o > 0; o >>= 1) { if (tid < o) sh[tid] += sh[tid + o]; __syncthreads(); }
  if (tid == 0) out[0] = s_nll + 100.0f * sh[0];
}

// ---------------- launcher ---------------------------------------------------
extern "C" void kernel_launch(void* const* d_in, const int* in_sizes, int n_in,
                              void* d_out, int out_size, void* d_ws, size_t ws_size,
                              hipStream_t stream)
{
  const float* x      = (const float*)d_in[0];
  const float* dX     = (const float*)d_in[1];
  const float* dT     = (const float*)d_in[2];
  const float* log_nu = (const float*)d_in[23];

  float* w     = (float*)d_ws;
  float* mu    = w;
  float* sig   = w + Bn;
  float* cdf   = w + 2 * Bn;
  float* parts = w + 3 * Bn;                    // 48 floats
  f16*  fragb  = (f16*)((char*)d_ws + 65536);   // 6 x 49152 halfs

  WSrc S;
  S.m[0] = (const float*)d_in[4];   // d_Whh0
  S.m[1] = (const float*)d_in[7];   // d_Wih1
  S.m[2] = (const float*)d_in[8];   // d_Whh1
  S.m[3] = (const float*)d_in[14];  // s_Whh0
  S.m[4] = (const float*)d_in[17];  // s_Wih1
  S.m[5] = (const float*)d_in[18];  // s_Whh1

  GruW Wd { fragb + (size_t)0*49152, fragb + (size_t)1*49152, fragb + (size_t)2*49152,
            (const float*)d_in[3], (const float*)d_in[5], (const float*)d_in[6],
            (const float*)d_in[9], (const float*)d_in[10],
            (const float*)d_in[11], (const float*)d_in[12] };
  GruW Ws { fragb + (size_t)3*49152, fragb + (size_t)4*49152, fragb + (size_t)5*49152,
            (const float*)d_in[13], (const float*)d_in[15], (const float*)d_in[16],
            (const float*)d_in[19], (const float*)d_in[20],
            (const float*)d_in[21], (const float*)d_in[22] };

  wconv_k <<<dim3(6*24), 256, 0, stream>>>(S, fragb);
  gru_mfma<<<dim3(256), 512, 0, stream>>>(x, Wd, Ws, mu, sig);
  stats_k <<<dim3(Bn/256), 256, 0, stream>>>(mu, sig, dX, dT, log_nu, cdf, parts);
  final_k <<<dim3(1), 256, 0, stream>>>(cdf, parts, (float*)d_out);
}

// Round 3
// 131.130 us; speedup vs baseline: 32.6786x; 2.4416x over previous
//
#include <hip/hip_runtime.h>
#include <math.h>

#define Bn 4096
#define Tn 40
#define Hn 128
#define NGRID 100
#define PI_F 3.14159265358979f
#define SQRT_2PI_F 2.50662827f
#define LOG2E 1.44269504088896f

typedef _Float16 f16;
typedef __attribute__((ext_vector_type(8))) _Float16 f16x8;
typedef __attribute__((ext_vector_type(4))) float f32x4;

struct GruW {
  const f16 *fWhh0, *fWih1, *fWhh1;     // fragment-layout fp16, gate-scaled
  const float *Wih0, *bih0, *bhh0, *bih1, *bhh1, *Wh, *bh;
};
struct WSrc { const float* m[6]; };

__device__ __forceinline__ float rcp_f(float x){ return __builtin_amdgcn_rcpf(x); }
__device__ __forceinline__ float ex2(float x){ return __builtin_amdgcn_exp2f(x); }
// LDS swizzle: r=row&15 -> XOR on byte bits 4..6. Reads (rows 0..15, fixed col) 2-way (free);
// writes (rows q,q+4,q+8,q+12, consecutive cols) land in 4 distinct 8-bank blocks (conflict-free).
__device__ __forceinline__ int swz(int r){
  return ((r&1)<<4) | ((((r>>1)^(r>>3))&1)<<5) | ((r&4)<<4);
}

// ---- fp32 [384][128] -> fp16 MFMA-B fragment layout, pre-scaled per gate:
//      r,z rows (n<256): * -log2e  (sigmoid exp2 folding)
//      n rows  (n>=256): * 2*log2e (tanh exp2 folding)
__global__ __launch_bounds__(256)
void wconv_k(WSrc S, f16* __restrict__ dst)
{
  const int m  = blockIdx.x / 24;
  const int nt = blockIdx.x % 24;
  const int ks = threadIdx.x >> 6;
  const int l  = threadIdx.x & 63;
  const float scale = (nt < 16) ? -LOG2E : (2.0f*LOG2E);
  const float* src = S.m[m] + (size_t)(nt*16 + (l&15))*Hn + ks*32 + (l>>4)*8;
  f16x8 o;
  #pragma unroll
  for (int jj = 0; jj < 8; ++jj) o[jj] = (f16)(src[jj] * scale);
  *((f16x8*)(dst + (size_t)m*49152) + ((nt*4 + ks)*64 + l)) = o;
}

// ---- fused 2-layer GRU, software-pipelined: one barrier per step.
//      Per iter i: L1(t=i) [reads h0(i), h1(i-1)] + L0(t=i+1) [reads h0(i)].
__global__ __launch_bounds__(512, 2)
void gru_mfma(const float* __restrict__ x, GruW Wd, GruW Ws,
              float* __restrict__ mu_out, float* __restrict__ sig_out)
{
  const int net = blockIdx.x >> 7;
  const int r0  = (blockIdx.x & 127) * 32;
  const GruW W  = net ? Ws : Wd;
  const int tid = threadIdx.x;
  const int w   = tid >> 6;        // wave 0..7 -> gate-col block w*16..+15
  const int l   = tid & 63;

  __shared__ __align__(16) char smem[131072];
  char* const h0b0 = smem;                 // [32][128] f16, swizzled (8KB each)
  char* const h0b1 = smem + 8192;
  char* const h1b0 = smem + 16384;
  char* const h1b1 = smem + 24576;
  char* const w1iL = smem + 32768;         // Wih1 fragments, 96KB

  // preload Wih1 fragments into LDS (once)
  {
    const int4* src = (const int4*)W.fWih1;
    int4* dst = (int4*)w1iL;
    #pragma unroll
    for (int k = 0; k < 12; ++k) dst[tid + k*512] = src[tid + k*512];
  }
  // zero h1(-1) buffer
  ((int4*)h1b1)[tid] = make_int4(0,0,0,0);

  const int j = w*16 + (l & 15);   // hidden column 0..127
  // pre-scaled per-column scalars
  const float wr_s = W.Wih0[j]      * (-LOG2E);
  const float wz_s = W.Wih0[Hn+j]   * (-LOG2E);
  const float wn_s = W.Wih0[2*Hn+j] * (2.0f*LOG2E);
  const float br0_s  = (W.bih0[j]      + W.bhh0[j])      * (-LOG2E);
  const float bz0_s  = (W.bih0[Hn+j]   + W.bhh0[Hn+j])   * (-LOG2E);
  const float bin0_s = W.bih0[2*Hn+j] * (2.0f*LOG2E);
  const float bnh0_s = W.bhh0[2*Hn+j] * (2.0f*LOG2E);
  const float br1_s  = (W.bih1[j]      + W.bhh1[j])      * (-LOG2E);
  const float bz1_s  = (W.bih1[Hn+j]   + W.bhh1[Hn+j])   * (-LOG2E);
  const float bin1_s = W.bih1[2*Hn+j] * (2.0f*LOG2E);
  const float bnh1_s = W.bhh1[2*Hn+j] * (2.0f*LOG2E);

  // persistent weight fragments: Whh0, Whh1
  const f16x8* F0  = (const f16x8*)W.fWhh0;
  const f16x8* F1h = (const f16x8*)W.fWhh1;
  f16x8 w0[3][4], w1h[3][4];
  #pragma unroll
  for (int g = 0; g < 3; ++g)
    #pragma unroll
    for (int ks = 0; ks < 4; ++ks) {
      const int idx = ((w + 8*g)*4 + ks)*64 + l;
      w0[g][ks]  = F0[idx];
      w1h[g][ks] = F1h[idx];
    }

  // A-fragment read offsets (swizzled), write offsets
  int roff[2][4], woff[2][4];
  {
    const int ra = l & 15, msk = swz(ra);
    #pragma unroll
    for (int mt = 0; mt < 2; ++mt)
      #pragma unroll
      for (int ks = 0; ks < 4; ++ks)
        roff[mt][ks] = (mt*16 + ra)*256 + ((ks*64 + ((l>>4)*16)) ^ msk);
  }
  {
    const int j2 = j*2;
    #pragma unroll
    for (int mt = 0; mt < 2; ++mt)
      #pragma unroll
      for (int q = 0; q < 4; ++q) {
        const int row = mt*16 + (l>>4)*4 + q;
        woff[mt][q] = row*256 + (j2 ^ swz(row & 15));
      }
  }
  int xoff[2][4];
  #pragma unroll
  for (int mt = 0; mt < 2; ++mt)
    #pragma unroll
    for (int q = 0; q < 4; ++q)
      xoff[mt][q] = (r0 + mt*16 + (l>>4)*4 + q)*Tn;

  float h0r[8], h1r[8] = {0,0,0,0,0,0,0,0}, s1r[8] = {0,0,0,0,0,0,0,0};

  __syncthreads();   // w1iL + h1b1 ready

  // ---- prologue: h0(0) from x(0) only (h0(-1)=0)
  #pragma unroll
  for (int mt = 0; mt < 2; ++mt)
    #pragma unroll
    for (int q = 0; q < 4; ++q) {
      const float xv = x[xoff[mt][q] + 0];
      const float rg = rcp_f(1.f + ex2(fmaf(xv, wr_s, br0_s)));
      const float zg = rcp_f(1.f + ex2(fmaf(xv, wz_s, bz0_s)));
      const float xn = fmaf(xv, wn_s, bin0_s);
      const float ng = fmaf(rcp_f(1.f + ex2(fmaf(rg, bnh0_s, xn))), -2.f, 1.f);
      const float hv = fmaf(-zg, ng, ng);
      h0r[mt*4+q] = hv;
      *(f16*)(h0b0 + woff[mt][q]) = (f16)hv;
    }
  __syncthreads();

  for (int i = 0; i < Tn; ++i) {
    const char* h0cur = (i&1) ? h0b1 : h0b0;
    char*       h0nxt = (i&1) ? h0b0 : h0b1;
    const char* h1prv = (i&1) ? h1b0 : h1b1;
    char*       h1cur = (i&1) ? h1b1 : h1b0;

    f32x4 aL0[3][2], aRZ[2][2], aXN[2], aHN[2];
    #pragma unroll
    for (int mt = 0; mt < 2; ++mt) {
      aL0[0][mt] = (f32x4){br0_s,br0_s,br0_s,br0_s};
      aL0[1][mt] = (f32x4){bz0_s,bz0_s,bz0_s,bz0_s};
      aL0[2][mt] = (f32x4){bnh0_s,bnh0_s,bnh0_s,bnh0_s};
      aRZ[0][mt] = (f32x4){br1_s,br1_s,br1_s,br1_s};
      aRZ[1][mt] = (f32x4){bz1_s,bz1_s,bz1_s,bz1_s};
      aXN[mt]    = (f32x4){bin1_s,bin1_s,bin1_s,bin1_s};
      aHN[mt]    = (f32x4){bnh1_s,bnh1_s,bnh1_s,bnh1_s};
    }

    // ---- A = h0(i): feeds both L0(t+1) (Whh0) and L1 x-side (Wih1)
    #pragma unroll
    for (int ks = 0; ks < 4; ++ks) {
      const f16x8 a0_0 = *(const f16x8*)(h0cur + roff[0][ks]);
      const f16x8 a0_1 = *(const f16x8*)(h0cur + roff[1][ks]);
      #pragma unroll
      for (int g = 0; g < 3; ++g) {
        const f16x8 bi = *(const f16x8*)(w1iL + (size_t)(((w + 8*g)*4 + ks)*64 + l)*16);
        aL0[g][0] = __builtin_amdgcn_mfma_f32_16x16x32_f16(a0_0, w0[g][ks], aL0[g][0], 0,0,0);
        aL0[g][1] = __builtin_amdgcn_mfma_f32_16x16x32_f16(a0_1, w0[g][ks], aL0[g][1], 0,0,0);
        if (g < 2) {
          aRZ[g][0] = __builtin_amdgcn_mfma_f32_16x16x32_f16(a0_0, bi, aRZ[g][0], 0,0,0);
          aRZ[g][1] = __builtin_amdgcn_mfma_f32_16x16x32_f16(a0_1, bi, aRZ[g][1], 0,0,0);
        } else {
          aXN[0] = __builtin_amdgcn_mfma_f32_16x16x32_f16(a0_0, bi, aXN[0], 0,0,0);
          aXN[1] = __builtin_amdgcn_mfma_f32_16x16x32_f16(a0_1, bi, aXN[1], 0,0,0);
        }
      }
    }
    // ---- A = h1(i-1): L1 h-side (Whh1)
    #pragma unroll
    for (int ks = 0; ks < 4; ++ks) {
      const f16x8 a1_0 = *(const f16x8*)(h1prv + roff[0][ks]);
      const f16x8 a1_1 = *(const f16x8*)(h1prv + roff[1][ks]);
      #pragma unroll
      for (int g = 0; g < 2; ++g) {
        aRZ[g][0] = __builtin_amdgcn_mfma_f32_16x16x32_f16(a1_0, w1h[g][ks], aRZ[g][0], 0,0,0);
        aRZ[g][1] = __builtin_amdgcn_mfma_f32_16x16x32_f16(a1_1, w1h[g][ks], aRZ[g][1], 0,0,0);
      }
      aHN[0] = __builtin_amdgcn_mfma_f32_16x16x32_f16(a1_0, w1h[2][ks], aHN[0], 0,0,0);
      aHN[1] = __builtin_amdgcn_mfma_f32_16x16x32_f16(a1_1, w1h[2][ks], aHN[1], 0,0,0);
    }

    // ---- L0 gates for t=i+1 -> h0(i+1)
    if (i < Tn-1) {
      #pragma unroll
      for (int mt = 0; mt < 2; ++mt)
        #pragma unroll
        for (int q = 0; q < 4; ++q) {
          const int e = mt*4+q;
          const float xv = x[xoff[mt][q] + i + 1];
          const float rg = rcp_f(1.f + ex2(fmaf(xv, wr_s, aL0[0][mt][q])));
          const float zg = rcp_f(1.f + ex2(fmaf(xv, wz_s, aL0[1][mt][q])));
          const float xn = fmaf(xv, wn_s, bin0_s);
          const float ng = fmaf(rcp_f(1.f + ex2(fmaf(rg, aL0[2][mt][q], xn))), -2.f, 1.f);
          const float hv = fmaf(zg, h0r[e] - ng, ng);
          h0r[e] = hv;
          *(f16*)(h0nxt + woff[mt][q]) = (f16)hv;
        }
    }
    // ---- L1 gates for t=i -> h1(i)
    #pragma unroll
    for (int mt = 0; mt < 2; ++mt)
      #pragma unroll
      for (int q = 0; q < 4; ++q) {
        const int e = mt*4+q;
        const float rg = rcp_f(1.f + ex2(aRZ[0][mt][q]));
        const float zg = rcp_f(1.f + ex2(aRZ[1][mt][q]));
        const float ng = fmaf(rcp_f(1.f + ex2(fmaf(rg, aHN[mt][q], aXN[mt][q]))), -2.f, 1.f);
        const float hv = fmaf(zg, h1r[e] - ng, ng);
        h1r[e] = hv;
        s1r[e] += hv;
        *(f16*)(h1cur + woff[mt][q]) = (f16)hv;
      }
    __syncthreads();   // single barrier per step
  }

  // ---- head: p[row] = h0.WhA + h1.WhB + mean_t(s1).WhC, reduce over j
  const float whA = W.Wh[j], whB = W.Wh[Hn+j], whC = W.Wh[2*Hn+j] * (1.0f/Tn);
  float* hredf = (float*)h0b0;    // reuse dead buffer: [32][8]
  #pragma unroll
  for (int mt = 0; mt < 2; ++mt)
    #pragma unroll
    for (int q = 0; q < 4; ++q) {
      const int e = mt*4+q;
      float p = h0r[e]*whA + h1r[e]*whB + s1r[e]*whC;
      p += __shfl_xor(p, 1); p += __shfl_xor(p, 2);
      p += __shfl_xor(p, 4); p += __shfl_xor(p, 8);
      if ((l & 15) == 0) hredf[(mt*16 + (l>>4)*4 + q)*8 + w] = p;
    }
  __syncthreads();
  if (tid < 32) {
    float s = W.bh[0];
    #pragma unroll
    for (int ww = 0; ww < 8; ++ww) s += hredf[tid*8 + ww];
    const float v = fminf(fmaxf(s, -20.f), 20.f);
    const int b = r0 + tid;
    if (net == 0) mu_out[b] = v;
    else          sig_out[b] = log1pf(__expf(v)) + 1e-4f;
  }
}

// ---------------- regularized incomplete beta (NR continued fraction) --------
__device__ float betacf_(float a, float b, float x)
{
  const float FPMIN = 1e-30f, EPS = 3e-7f;
  const float qab = a + b, qap = a + 1.f, qam = a - 1.f;
  float c = 1.f;
  float d = 1.f - qab * x / qap;
  if (fabsf(d) < FPMIN) d = FPMIN;
  d = 1.f / d;
  float h = d;
  for (int m = 1; m <= 100; ++m) {
    const float m2 = 2.f * m;
    float aa = m * (b - m) * x / ((qam + m2) * (a + m2));
    d = 1.f + aa * d; if (fabsf(d) < FPMIN) d = FPMIN;
    c = 1.f + aa / c; if (fabsf(c) < FPMIN) c = FPMIN;
    d = 1.f / d; h *= d * c;
    aa = -(a + m) * (qab + m) * x / ((a + m2) * (qap + m2));
    d = 1.f + aa * d; if (fabsf(d) < FPMIN) d = FPMIN;
    c = 1.f + aa / c; if (fabsf(c) < FPMIN) c = FPMIN;
    d = 1.f / d;
    const float del = d * c; h *= del;
    if (fabsf(del - 1.f) < EPS) break;
  }
  return h;
}

__device__ float betainc_(float a, float b, float x, float cx)
{
  if (x  <= 0.f) return 0.f;
  if (cx <= 0.f) return 1.f;
  const float lx  = (x  > 0.5f) ? log1pf(-cx) : logf(x);
  const float lcx = (cx > 0.5f) ? log1pf(-x)  : logf(cx);
  const float bt = expf(lgammaf(a+b) - lgammaf(a) - lgammaf(b) + a*lx + b*lcx);
  if (x < (a + 1.f) / (a + b + 2.f)) return bt * betacf_(a, b, x) / a;
  else                               return 1.f - bt * betacf_(b, a, cx) / b;
}

__global__ __launch_bounds__(256)
void stats_k(const float* __restrict__ mu, const float* __restrict__ sig,
             const float* __restrict__ dX, const float* __restrict__ dTp,
             const float* __restrict__ log_nu,
             float* __restrict__ cdf_out, float* __restrict__ parts)
{
  const int tid = threadIdx.x;
  const int b = blockIdx.x * 256 + tid;
  const float dT = dTp[0];
  const float df = fminf(fmaxf(expf(log_nu[0]), 2.1f), 30.0f);

  const float m = mu[b], s = sig[b];
  const float scale = s * sqrtf(dT);
  const float y  = (dX[b] - m * dT) / scale;
  const float y2 = y * y;
  const float lp = lgammaf((df + 1.f) * 0.5f) - lgammaf(df * 0.5f)
                 - 0.5f * logf(df * PI_F) - logf(scale)
                 - (df + 1.f) * 0.5f * log1pf(y2 / df);
  const float den = df + y2;
  const float xb = df / den, cxb = y2 / den;
  const float ib = betainc_(0.5f * df, 0.5f, xb, cxb);
  float cdf = (y <= 0.f) ? 0.5f * ib : 1.f - 0.5f * ib;
  cdf = fminf(fmaxf(cdf, 1e-6f), 1.f - 1e-6f);
  cdf_out[b] = cdf;

  __shared__ float red[256];
  red[tid] = lp; __syncthreads();
  for (int o = 128; o > 0; o >>= 1) { if (tid < o) red[tid] += red[tid + o]; __syncthreads(); }
  if (tid == 0) parts[blockIdx.x] = red[0];
  __syncthreads();
  red[tid] = cdf; __syncthreads();
  for (int o = 128; o > 0; o >>= 1) { if (tid < o) red[tid] += red[tid + o]; __syncthreads(); }
  if (tid == 0) parts[16 + blockIdx.x] = red[0];
  __syncthreads();
  red[tid] = cdf * cdf; __syncthreads();
  for (int o = 128; o > 0; o >>= 1) { if (tid < o) red[tid] += red[tid + o]; __syncthreads(); }
  if (tid == 0) parts[32 + blockIdx.x] = red[0];
}

// ---------------- KDE: one block per grid point -------------------------------
__global__ __launch_bounds__(256)
void kde_k(const float* __restrict__ cdf, const float* __restrict__ parts,
           float* __restrict__ pen)
{
  const int tid = threadIdx.x;
  float sc = 0.f, sc2 = 0.f;
  #pragma unroll
  for (int i = 0; i < 16; ++i) { sc += parts[16+i]; sc2 += parts[32+i]; }
  const float mean = sc / (float)Bn;
  const float var  = (sc2 - (float)Bn * mean * mean) / (float)(Bn - 1);
  const float sd   = sqrtf(fmaxf(var, 0.f));
  const float hbw  = 1.06f * sd * 0.18946457f + 1e-5f;   // 4096^-0.2
  const float inv  = 1.0f / hbw;
  const float u    = (float)blockIdx.x / (float)(NGRID - 1);
  const float c    = -0.5f * LOG2E;

  float acc = 0.f;
  for (int k = tid; k < Bn; k += 256) {
    const float d = (u - cdf[k]) * inv;
    acc += ex2(d * d * c);
  }
  __shared__ float sh[256];
  sh[tid] = acc; __syncthreads();
  for (int o = 128; o > 0; o >>= 1) { if (tid < o) sh[tid] += sh[tid + o]; __syncthreads(); }
  if (tid == 0) {
    const float f = sh[0] / (SQRT_2PI_F * (float)Bn * hbw);
    const float dd = f - 1.0f;
    pen[blockIdx.x] = dd * dd * (1.0f / (float)NGRID);
  }
}

__global__ __launch_bounds__(128)
void finish_k(const float* __restrict__ parts, const float* __restrict__ pen,
              float* __restrict__ out)
{
  const int tid = threadIdx.x;
  __shared__ float sh[128];
  sh[tid] = (tid < NGRID) ? pen[tid] : 0.f;
  __syncthreads();
  for (int o = 64; o > 0; o >>= 1) { if (tid < o) sh[tid] += sh[tid + o]; __syncthreads(); }
  if (tid == 0) {
    float slp = 0.f;
    #pragma unroll
    for (int i = 0; i < 16; ++i) slp += parts[i];
    out[0] = (-slp / (float)Bn) + 100.0f * sh[0];
  }
}

// ---------------- launcher ---------------------------------------------------
extern "C" void kernel_launch(void* const* d_in, const int* in_sizes, int n_in,
                              void* d_out, int out_size, void* d_ws, size_t ws_size,
                              hipStream_t stream)
{
  const float* x      = (const float*)d_in[0];
  const float* dX     = (const float*)d_in[1];
  const float* dT     = (const float*)d_in[2];
  const float* log_nu = (const float*)d_in[23];

  float* w     = (float*)d_ws;
  float* mu    = w;
  float* sig   = w + Bn;
  float* cdf   = w + 2 * Bn;
  float* parts = w + 3 * Bn;                    // 48 floats
  float* pen   = w + 3 * Bn + 48;               // 100 floats
  f16*  fragb  = (f16*)((char*)d_ws + 65536);   // 6 x 49152 halfs

  WSrc S;
  S.m[0] = (const float*)d_in[4];   // d_Whh0
  S.m[1] = (const float*)d_in[7];   // d_Wih1
  S.m[2] = (const float*)d_in[8];   // d_Whh1
  S.m[3] = (const float*)d_in[14];  // s_Whh0
  S.m[4] = (const float*)d_in[17];  // s_Wih1
  S.m[5] = (const float*)d_in[18];  // s_Whh1

  GruW Wd { fragb + (size_t)0*49152, fragb + (size_t)1*49152, fragb + (size_t)2*49152,
            (const float*)d_in[3], (const float*)d_in[5], (const float*)d_in[6],
            (const float*)d_in[9], (const float*)d_in[10],
            (const float*)d_in[11], (const float*)d_in[12] };
  GruW Ws { fragb + (size_t)3*49152, fragb + (size_t)4*49152, fragb + (size_t)5*49152,
            (const float*)d_in[13], (const float*)d_in[15], (const float*)d_in[16],
            (const float*)d_in[19], (const float*)d_in[20],
            (const float*)d_in[21], (const float*)d_in[22] };

  wconv_k <<<dim3(6*24), 256, 0, stream>>>(S, fragb);
  gru_mfma<<<dim3(256), 512, 0, stream>>>(x, Wd, Ws, mu, sig);
  stats_k <<<dim3(Bn/256), 256, 0, stream>>>(mu, sig, dX, dT, log_nu, cdf, parts);
  kde_k   <<<dim3(NGRID), 256, 0, stream>>>(cdf, parts, pen);
  finish_k<<<dim3(1), 128, 0, stream>>>(parts, pen, (float*)d_out);
}